// Round 1
// baseline (236.734 us; speedup 1.0000x reference)
//
#include <hip/hip_runtime.h>
#include <math.h>

// Problem constants (from reference setup_inputs)
#define BB 512
#define HH 512
#define RR 2048
#define CC 64
#define OUTD 202          // 3*64 + 2*3 + 4
// params workspace layout per batch (floats), 16B-aligned sections
#define PSTRIDE 208
#define K_OFF 0
#define E_OFF 64
#define A_OFF 128
#define S_OFF 192         // 7 softmaxed shift weights
#define COMBO_OFF 199     // beta / k_n
#define G_OFF 200
#define GAMMA_OFF 201

__device__ __forceinline__ float softplusf_(float x) {
    return (x > 20.f) ? x : log1pf(expf(x));
}
__device__ __forceinline__ float sigmoidf_(float x) {
    return 1.f / (1.f + expf(-x));
}

// ---------------------------------------------------------------------------
// Kernel A: z = h @ fc_w^T + fc_b, then activations -> packed params in ws.
// grid 64 blocks x 256 threads; each block handles 8 batch rows so fc_w
// (202x512 = 414KB) is swept only 64 times (L2-resident).
// ---------------------------------------------------------------------------
__global__ __launch_bounds__(256) void params_kernel(
    const float* __restrict__ h, const float* __restrict__ fc_w,
    const float* __restrict__ fc_b, float* __restrict__ pw)
{
    __shared__ float h_sh[8][HH];      // 16 KB
    __shared__ float z_sh[8][204];     // ~6.5 KB
    const int tid = threadIdx.x;
    const int b0 = blockIdx.x * 8;

    for (int idx = tid; idx < 8 * HH; idx += 256) {
        int j = idx >> 9, i = idx & 511;
        h_sh[j][i] = h[(size_t)(b0 + j) * HH + i];
    }
    __syncthreads();

    if (tid < OUTD) {
        float acc[8];
        #pragma unroll
        for (int j = 0; j < 8; ++j) acc[j] = 0.f;
        const float4* wr4 = (const float4*)(fc_w + (size_t)tid * HH);
        for (int i4 = 0; i4 < HH / 4; ++i4) {
            float4 wv = wr4[i4];
            int i = i4 * 4;
            #pragma unroll
            for (int j = 0; j < 8; ++j) {
                acc[j] = fmaf(wv.x, h_sh[j][i + 0], acc[j]);
                acc[j] = fmaf(wv.y, h_sh[j][i + 1], acc[j]);
                acc[j] = fmaf(wv.z, h_sh[j][i + 2], acc[j]);
                acc[j] = fmaf(wv.w, h_sh[j][i + 3], acc[j]);
            }
        }
        float bias = fc_b[tid];
        #pragma unroll
        for (int j = 0; j < 8; ++j) z_sh[j][tid] = acc[j] + bias;
    }
    __syncthreads();

    // elementwise activations: k(tanh), g(sigmoid), gamma(softplus+1),
    // e(sigmoid), a(tanh). beta and s handled below (need reductions).
    for (int idx = tid; idx < 8 * OUTD; idx += 256) {
        int j = idx / OUTD;
        int t = idx - j * OUTD;
        float z = z_sh[j][t];
        float* p = pw + (size_t)(b0 + j) * PSTRIDE;
        if (t < 64)            p[K_OFF + t] = tanhf(z);
        else if (t == 65)      p[G_OFF] = sigmoidf_(z);
        else if (t == 73)      p[GAMMA_OFF] = softplusf_(z) + 1.f;
        else if (t >= 74 && t < 138) p[E_OFF + (t - 74)] = sigmoidf_(z);
        else if (t >= 138)     p[A_OFF + (t - 138)] = tanhf(z);
        // t==64 (beta), t in [66,73) (s raw): consumed below from z_sh
    }
    __syncthreads();

    if (tid < 8) {
        int j = tid;
        float* p = pw + (size_t)(b0 + j) * PSTRIDE;
        float ss = 0.f;
        for (int c = 0; c < 64; ++c) {
            float kv = tanhf(z_sh[j][c]);
            ss += kv * kv;
        }
        float kn = fmaxf(sqrtf(ss), 1e-8f);
        float beta = softplusf_(z_sh[j][64]);
        p[COMBO_OFF] = beta / kn;
        // softmax over 7 shift logits
        float mx = -1e30f;
        for (int q = 0; q < 7; ++q) mx = fmaxf(mx, z_sh[j][66 + q]);
        float ev[7], se = 0.f;
        for (int q = 0; q < 7; ++q) { ev[q] = expf(z_sh[j][66 + q] - mx); se += ev[q]; }
        float inv = 1.f / se;
        for (int q = 0; q < 7; ++q) p[S_OFF + q] = ev[q] * inv;
    }
}

// ---------------------------------------------------------------------------
// Block reductions for 1024 threads (16 waves)
// ---------------------------------------------------------------------------
__device__ __forceinline__ float block_reduce_sum(float v, float* red) {
    #pragma unroll
    for (int m = 1; m < 64; m <<= 1) v += __shfl_xor(v, m, 64);
    int wid = threadIdx.x >> 6;
    if ((threadIdx.x & 63) == 0) red[wid] = v;
    __syncthreads();
    if (threadIdx.x < 16) {
        float x = red[threadIdx.x];
        #pragma unroll
        for (int m = 1; m < 16; m <<= 1) x += __shfl_xor(x, m, 64);
        if (threadIdx.x == 0) red[0] = x;
    }
    __syncthreads();
    float r = red[0];
    __syncthreads();
    return r;
}

__device__ __forceinline__ float block_reduce_max(float v, float* red) {
    #pragma unroll
    for (int m = 1; m < 64; m <<= 1) v = fmaxf(v, __shfl_xor(v, m, 64));
    int wid = threadIdx.x >> 6;
    if ((threadIdx.x & 63) == 0) red[wid] = v;
    __syncthreads();
    if (threadIdx.x < 16) {
        float x = red[threadIdx.x];
        #pragma unroll
        for (int m = 1; m < 16; m <<= 1) x = fmaxf(x, __shfl_xor(x, m, 64));
        if (threadIdx.x == 0) red[0] = x;
    }
    __syncthreads();
    float r = red[0];
    __syncthreads();
    return r;
}

// ---------------------------------------------------------------------------
// Kernel B: fused per-batch main kernel. grid = 512 blocks x 1024 threads
// (exactly 2 blocks/CU). 16 lanes per memory row (float4/lane).
// phase1: num & ||m|| -> raw score in LDS
// phase2: softmax_R -> interp w/ prev_w -> 7-tap circular conv -> pow -> norm
// phase3: new_mem = mem*(1 - w*e) + w*a  (slice re-read is L2/L3-warm)
// ---------------------------------------------------------------------------
__global__ __launch_bounds__(1024) void main_kernel(
    const float* __restrict__ memory, const float* __restrict__ prev_w,
    const float* __restrict__ pw, float* __restrict__ out_w,
    float* __restrict__ out_mem)
{
    __shared__ float sc[RR];       // 8 KB: raw score -> exp -> w_p
    __shared__ float wg[RR];       // 8 KB: gated weights -> final w
    __shared__ float red[16];
    __shared__ float sp[12];       // s[0..6], g, gamma, combo

    const int b = blockIdx.x;
    const int tid = threadIdx.x;
    const int lane16 = tid & 15;
    const int rgrp = tid >> 4;     // 0..63 row-group
    const float* p = pw + (size_t)b * PSTRIDE;

    const float4 k4 = *(const float4*)(p + K_OFF + lane16 * 4);
    const float4 e4 = *(const float4*)(p + E_OFF + lane16 * 4);
    const float4 a4 = *(const float4*)(p + A_OFF + lane16 * 4);
    if (tid < 10) {
        float v;
        if (tid < 7)       v = p[S_OFF + tid];
        else if (tid == 7) v = p[G_OFF];
        else if (tid == 8) v = p[GAMMA_OFF];
        else               v = p[COMBO_OFF];
        sp[tid] = v;
    }

    const float* memb = memory + (size_t)b * RR * CC;

    // ---- phase 1: cosine-similarity numerator & row norms ----
    #pragma unroll 4
    for (int r = rgrp; r < RR; r += 64) {
        float4 m4 = *(const float4*)(memb + (size_t)r * CC + lane16 * 4);
        float num = m4.x * k4.x + m4.y * k4.y + m4.z * k4.z + m4.w * k4.w;
        float ssq = m4.x * m4.x + m4.y * m4.y + m4.z * m4.z + m4.w * m4.w;
        #pragma unroll
        for (int m = 1; m < 16; m <<= 1) {
            num += __shfl_xor(num, m, 64);
            ssq += __shfl_xor(ssq, m, 64);
        }
        if (lane16 == 0) {
            float mn = fmaxf(sqrtf(ssq), 1e-8f);
            sc[r] = num / mn;     // combo (=beta/k_n) applied in phase 2
        }
    }
    __syncthreads();

    const float g = sp[7], gamma = sp[8], combo = sp[9];
    const float s0 = sp[0], s1 = sp[1], s2 = sp[2], s3 = sp[3],
                s4 = sp[4], s5 = sp[5], s6 = sp[6];

    // ---- phase 2a: softmax over R ----
    float lm = -1e30f;
    for (int r = tid; r < RR; r += 1024) lm = fmaxf(lm, combo * sc[r]);
    const float mx = block_reduce_max(lm, red);

    float ls = 0.f;
    for (int r = tid; r < RR; r += 1024) {
        float ev = expf(combo * sc[r] - mx);
        sc[r] = ev;
        ls += ev;
    }
    const float se = block_reduce_sum(ls, red);
    const float invse = 1.f / se;

    // ---- phase 2b: gate with prev_w ----
    for (int r = tid; r < RR; r += 1024) {
        float wc = sc[r] * invse;
        wg[r] = g * wc + (1.f - g) * prev_w[(size_t)b * RR + r];
    }
    __syncthreads();

    // ---- phase 2c: 7-tap circular conv + sharpen ----
    float lp = 0.f;
    for (int r = tid; r < RR; r += 1024) {
        float acc = s0 * wg[(r - 3) & (RR - 1)]
                  + s1 * wg[(r - 2) & (RR - 1)]
                  + s2 * wg[(r - 1) & (RR - 1)]
                  + s3 * wg[r]
                  + s4 * wg[(r + 1) & (RR - 1)]
                  + s5 * wg[(r + 2) & (RR - 1)]
                  + s6 * wg[(r + 3) & (RR - 1)];
        float wp = powf(acc, gamma);
        sc[r] = wp;
        lp += wp;
    }
    const float ps = block_reduce_sum(lp, red);   // syncthreads inside: conv reads done
    const float invp = 1.f / (ps + 1e-16f);

    for (int r = tid; r < RR; r += 1024) {
        float wv = sc[r] * invp;
        wg[r] = wv;                                // final w, reused in phase 3
        out_w[(size_t)b * RR + r] = wv;
    }
    __syncthreads();

    // ---- phase 3: memory update ----
    float* omb = out_mem + (size_t)b * RR * CC;
    #pragma unroll 4
    for (int r = rgrp; r < RR; r += 64) {
        float wv = wg[r];
        float4 m4 = *(const float4*)(memb + (size_t)r * CC + lane16 * 4);
        float4 o;
        o.x = m4.x * (1.f - wv * e4.x) + wv * a4.x;
        o.y = m4.y * (1.f - wv * e4.y) + wv * a4.y;
        o.z = m4.z * (1.f - wv * e4.z) + wv * a4.z;
        o.w = m4.w * (1.f - wv * e4.w) + wv * a4.w;
        *(float4*)(omb + (size_t)r * CC + lane16 * 4) = o;
    }
}

extern "C" void kernel_launch(void* const* d_in, const int* in_sizes, int n_in,
                              void* d_out, int out_size, void* d_ws, size_t ws_size,
                              hipStream_t stream) {
    const float* h      = (const float*)d_in[0];
    const float* prev_w = (const float*)d_in[1];
    const float* memory = (const float*)d_in[2];
    const float* fc_w   = (const float*)d_in[3];
    const float* fc_b   = (const float*)d_in[4];

    float* pw      = (float*)d_ws;              // 512*208*4 = 416 KB
    float* out_w   = (float*)d_out;             // B*R
    float* out_mem = out_w + (size_t)BB * RR;   // B*R*C

    params_kernel<<<64, 256, 0, stream>>>(h, fc_w, fc_b, pw);
    main_kernel<<<BB, 1024, 0, stream>>>(memory, prev_w, pw, out_w, out_mem);
}

// Round 2
// 209.617 us; speedup vs baseline: 1.1294x; 1.1294x over previous
//
#include <hip/hip_runtime.h>
#include <math.h>

// Problem constants (from reference setup_inputs)
#define BB 512
#define HH 512
#define RR 2048
#define CC 64
#define OUTD 202          // 3*64 + 2*3 + 4
// params workspace layout per batch (floats)
#define PSTRIDE 208
#define K_OFF 0
#define E_OFF 64
#define A_OFF 128
#define S_OFF 192         // 7 softmaxed shift weights
#define COMBO_OFF 199     // beta / k_n
#define G_OFF 200
#define GAMMA_OFF 201

typedef float f32x4 __attribute__((ext_vector_type(4)));

__device__ __forceinline__ float softplusf_(float x) {
    return (x > 20.f) ? x : log1pf(expf(x));
}
__device__ __forceinline__ float sigmoidf_(float x) {
    return 1.f / (1.f + expf(-x));
}

// ---------------------------------------------------------------------------
// Kernel A: z = h @ fc_w^T + fc_b, activations -> packed params in ws.
// 64 blocks x 256 threads; 8 batch rows/block so fc_w (414KB) stays L2-hot.
// ---------------------------------------------------------------------------
__global__ __launch_bounds__(256) void params_kernel(
    const float* __restrict__ h, const float* __restrict__ fc_w,
    const float* __restrict__ fc_b, float* __restrict__ pw)
{
    __shared__ float h_sh[8][HH];
    __shared__ float z_sh[8][204];
    const int tid = threadIdx.x;
    const int b0 = blockIdx.x * 8;

    for (int idx = tid; idx < 8 * HH; idx += 256) {
        int j = idx >> 9, i = idx & 511;
        h_sh[j][i] = h[(size_t)(b0 + j) * HH + i];
    }
    __syncthreads();

    if (tid < OUTD) {
        float acc[8];
        #pragma unroll
        for (int j = 0; j < 8; ++j) acc[j] = 0.f;
        const float4* wr4 = (const float4*)(fc_w + (size_t)tid * HH);
        for (int i4 = 0; i4 < HH / 4; ++i4) {
            float4 wv = wr4[i4];
            int i = i4 * 4;
            #pragma unroll
            for (int j = 0; j < 8; ++j) {
                acc[j] = fmaf(wv.x, h_sh[j][i + 0], acc[j]);
                acc[j] = fmaf(wv.y, h_sh[j][i + 1], acc[j]);
                acc[j] = fmaf(wv.z, h_sh[j][i + 2], acc[j]);
                acc[j] = fmaf(wv.w, h_sh[j][i + 3], acc[j]);
            }
        }
        float bias = fc_b[tid];
        #pragma unroll
        for (int j = 0; j < 8; ++j) z_sh[j][tid] = acc[j] + bias;
    }
    __syncthreads();

    for (int idx = tid; idx < 8 * OUTD; idx += 256) {
        int j = idx / OUTD;
        int t = idx - j * OUTD;
        float z = z_sh[j][t];
        float* p = pw + (size_t)(b0 + j) * PSTRIDE;
        if (t < 64)            p[K_OFF + t] = tanhf(z);
        else if (t == 65)      p[G_OFF] = sigmoidf_(z);
        else if (t == 73)      p[GAMMA_OFF] = softplusf_(z) + 1.f;
        else if (t >= 74 && t < 138) p[E_OFF + (t - 74)] = sigmoidf_(z);
        else if (t >= 138)     p[A_OFF + (t - 138)] = tanhf(z);
    }
    __syncthreads();

    if (tid < 8) {
        int j = tid;
        float* p = pw + (size_t)(b0 + j) * PSTRIDE;
        float ss = 0.f;
        for (int c = 0; c < 64; ++c) {
            float kv = tanhf(z_sh[j][c]);
            ss += kv * kv;
        }
        float kn = fmaxf(sqrtf(ss), 1e-8f);
        float beta = softplusf_(z_sh[j][64]);
        p[COMBO_OFF] = beta / kn;
        float mx = -1e30f;
        for (int q = 0; q < 7; ++q) mx = fmaxf(mx, z_sh[j][66 + q]);
        float ev[7], se = 0.f;
        for (int q = 0; q < 7; ++q) { ev[q] = expf(z_sh[j][66 + q] - mx); se += ev[q]; }
        float inv = 1.f / se;
        for (int q = 0; q < 7; ++q) p[S_OFF + q] = ev[q] * inv;
    }
}

// ---------------------------------------------------------------------------
// Kernel S: raw cosine scores sc[b][r] = (k . m_r) / max(||m_r||, eps).
// 2048 blocks x 256 threads (8 blocks/CU) — pure streaming read of memory.
// 16 lanes per row (float4/lane), shfl16 reduce.
// ---------------------------------------------------------------------------
__global__ __launch_bounds__(256) void score_kernel(
    const float* __restrict__ memory, const float* __restrict__ pw,
    float* __restrict__ sc)
{
    const int tid = threadIdx.x;
    const int b = blockIdx.x >> 2;
    const int rbase = (blockIdx.x & 3) * 512;
    const int lane16 = tid & 15;
    const int rgrp = tid >> 4;            // 0..15
    const float* p = pw + (size_t)b * PSTRIDE;
    const float4 k4 = *(const float4*)(p + K_OFF + lane16 * 4);
    const float* memb = memory + (size_t)b * RR * CC;

    #pragma unroll 4
    for (int i = 0; i < 32; ++i) {
        int r = rbase + i * 16 + rgrp;
        float4 m4 = *(const float4*)(memb + (size_t)r * CC + lane16 * 4);
        float num = m4.x * k4.x + m4.y * k4.y + m4.z * k4.z + m4.w * k4.w;
        float ssq = m4.x * m4.x + m4.y * m4.y + m4.z * m4.z + m4.w * m4.w;
        #pragma unroll
        for (int m = 1; m < 16; m <<= 1) {
            num += __shfl_xor(num, m, 64);
            ssq += __shfl_xor(ssq, m, 64);
        }
        if (lane16 == 0)
            sc[(size_t)b * RR + r] = num / fmaxf(sqrtf(ssq), 1e-8f);
    }
}

// ---------------------------------------------------------------------------
// Kernel W: per-batch softmax (max-free: |combo*sc| <= beta, exp safe in f32)
// -> gate with prev_w -> 7-tap circular conv -> pow -> normalize -> out_w.
// 512 blocks x 256 threads; all row state in LDS.
// ---------------------------------------------------------------------------
__device__ __forceinline__ float block_reduce_sum256(float v, float* red) {
    #pragma unroll
    for (int m = 1; m < 64; m <<= 1) v += __shfl_xor(v, m, 64);
    int wid = threadIdx.x >> 6;
    if ((threadIdx.x & 63) == 0) red[wid] = v;
    __syncthreads();
    float x = red[0] + red[1] + red[2] + red[3];
    __syncthreads();
    return x;
}

__global__ __launch_bounds__(256) void weight_kernel(
    const float* __restrict__ sc, const float* __restrict__ prev_w,
    const float* __restrict__ pw, float* __restrict__ out_w)
{
    __shared__ float buf[RR];
    __shared__ float wg[RR];
    __shared__ float red[4];
    const int b = blockIdx.x;
    const int tid = threadIdx.x;
    const float* p = pw + (size_t)b * PSTRIDE;
    const float combo = p[COMBO_OFF];
    const float g = p[G_OFF];
    const float gamma = p[GAMMA_OFF];
    const float s0 = p[S_OFF + 0], s1 = p[S_OFF + 1], s2 = p[S_OFF + 2],
                s3 = p[S_OFF + 3], s4 = p[S_OFF + 4], s5 = p[S_OFF + 5],
                s6 = p[S_OFF + 6];

    // exp + sum (no max subtraction; mathematically identical softmax)
    float ls = 0.f;
    for (int r = tid; r < RR; r += 256) {
        float ev = expf(combo * sc[(size_t)b * RR + r]);
        buf[r] = ev;
        ls += ev;
    }
    const float se = block_reduce_sum256(ls, red);
    const float invse = 1.f / se;

    // gate with prev_w
    for (int r = tid; r < RR; r += 256) {
        wg[r] = g * (buf[r] * invse) + (1.f - g) * prev_w[(size_t)b * RR + r];
    }
    __syncthreads();

    // 7-tap circular conv + sharpen
    float lp = 0.f;
    for (int r = tid; r < RR; r += 256) {
        float acc = s0 * wg[(r - 3) & (RR - 1)]
                  + s1 * wg[(r - 2) & (RR - 1)]
                  + s2 * wg[(r - 1) & (RR - 1)]
                  + s3 * wg[r]
                  + s4 * wg[(r + 1) & (RR - 1)]
                  + s5 * wg[(r + 2) & (RR - 1)]
                  + s6 * wg[(r + 3) & (RR - 1)];
        float wp = powf(acc, gamma);
        buf[r] = wp;
        lp += wp;
    }
    const float ps = block_reduce_sum256(lp, red);
    const float invp = 1.f / (ps + 1e-16f);

    for (int r = tid; r < RR; r += 256) {
        out_w[(size_t)b * RR + r] = buf[r] * invp;
    }
}

// ---------------------------------------------------------------------------
// Kernel U: new_mem = mem*(1 - w*e) + w*a. Pure grid-stride streaming.
// 2048 blocks x 256 threads; nontemporal stores keep the L3-resident
// memory array (filled by score_kernel) from being evicted by the writes.
// ---------------------------------------------------------------------------
__global__ __launch_bounds__(256) void update_kernel(
    const float* __restrict__ memory, const float* __restrict__ w,
    const float* __restrict__ pw, float* __restrict__ out_mem)
{
    const size_t N4 = (size_t)BB * RR * CC / 4;     // 16,777,216 float4s
    const size_t stride = (size_t)2048 * 256;
    const f32x4* m4p = (const f32x4*)memory;
    f32x4* o4p = (f32x4*)out_mem;

    #pragma unroll 2
    for (size_t idx = (size_t)blockIdx.x * 256 + threadIdx.x; idx < N4;
         idx += stride) {
        int br = (int)(idx >> 4);                   // b*RR + r
        int b  = (int)(idx >> 15);
        int c4 = (int)(idx & 15);
        const float* p = pw + (size_t)b * PSTRIDE;
        float wv = w[br];
        f32x4 e4 = *(const f32x4*)(p + E_OFF + c4 * 4);
        f32x4 a4 = *(const f32x4*)(p + A_OFF + c4 * 4);
        f32x4 m4 = m4p[idx];
        f32x4 o;
        o.x = m4.x * (1.f - wv * e4.x) + wv * a4.x;
        o.y = m4.y * (1.f - wv * e4.y) + wv * a4.y;
        o.z = m4.z * (1.f - wv * e4.z) + wv * a4.z;
        o.w = m4.w * (1.f - wv * e4.w) + wv * a4.w;
        __builtin_nontemporal_store(o, &o4p[idx]);
    }
}

extern "C" void kernel_launch(void* const* d_in, const int* in_sizes, int n_in,
                              void* d_out, int out_size, void* d_ws, size_t ws_size,
                              hipStream_t stream) {
    const float* h      = (const float*)d_in[0];
    const float* prev_w = (const float*)d_in[1];
    const float* memory = (const float*)d_in[2];
    const float* fc_w   = (const float*)d_in[3];
    const float* fc_b   = (const float*)d_in[4];

    float* pw      = (float*)d_ws;              // 512*208*4 = 416 KB
    float* out_w   = (float*)d_out;             // B*R
    float* out_mem = out_w + (size_t)BB * RR;   // B*R*C
    // scratch for raw scores: head of out_mem region (4 MB), fully
    // overwritten by update_kernel afterwards and never read by it.
    float* sc      = out_mem;

    params_kernel<<<64, 256, 0, stream>>>(h, fc_w, fc_b, pw);
    score_kernel<<<BB * 4, 256, 0, stream>>>(memory, pw, sc);
    weight_kernel<<<BB, 256, 0, stream>>>(sc, prev_w, pw, out_w);
    update_kernel<<<2048, 256, 0, stream>>>(memory, out_w, pw, out_mem);
}

// Round 3
// 199.125 us; speedup vs baseline: 1.1889x; 1.0527x over previous
//
#include <hip/hip_runtime.h>
#include <math.h>

// Problem constants (from reference setup_inputs)
#define BB 512
#define HH 512
#define RR 2048
#define CC 64
#define OUTD 202          // 3*64 + 2*3 + 4
// params workspace layout per batch (floats)
#define PSTRIDE 208
#define K_OFF 0
#define E_OFF 64
#define A_OFF 128
#define S_OFF 192         // 7 softmaxed shift weights
#define COMBO_OFF 199     // beta / k_n
#define G_OFF 200
#define GAMMA_OFF 201

typedef float f32x4 __attribute__((ext_vector_type(4)));

__device__ __forceinline__ float softplusf_(float x) {
    return (x > 20.f) ? x : log1pf(expf(x));
}
__device__ __forceinline__ float sigmoidf_(float x) {
    return 1.f / (1.f + expf(-x));
}

// ---------------------------------------------------------------------------
// Kernel A: z = h @ fc_w^T + fc_b, activations -> packed params in ws.
// 64 blocks x 256 threads; 8 batch rows/block so fc_w (414KB) stays L2-hot.
// ---------------------------------------------------------------------------
__global__ __launch_bounds__(256) void params_kernel(
    const float* __restrict__ h, const float* __restrict__ fc_w,
    const float* __restrict__ fc_b, float* __restrict__ pw)
{
    __shared__ float h_sh[8][HH];
    __shared__ float z_sh[8][204];
    const int tid = threadIdx.x;
    const int b0 = blockIdx.x * 8;

    for (int idx = tid; idx < 8 * HH; idx += 256) {
        int j = idx >> 9, i = idx & 511;
        h_sh[j][i] = h[(size_t)(b0 + j) * HH + i];
    }
    __syncthreads();

    if (tid < OUTD) {
        float acc[8];
        #pragma unroll
        for (int j = 0; j < 8; ++j) acc[j] = 0.f;
        const float4* wr4 = (const float4*)(fc_w + (size_t)tid * HH);
        for (int i4 = 0; i4 < HH / 4; ++i4) {
            float4 wv = wr4[i4];
            int i = i4 * 4;
            #pragma unroll
            for (int j = 0; j < 8; ++j) {
                acc[j] = fmaf(wv.x, h_sh[j][i + 0], acc[j]);
                acc[j] = fmaf(wv.y, h_sh[j][i + 1], acc[j]);
                acc[j] = fmaf(wv.z, h_sh[j][i + 2], acc[j]);
                acc[j] = fmaf(wv.w, h_sh[j][i + 3], acc[j]);
            }
        }
        float bias = fc_b[tid];
        #pragma unroll
        for (int j = 0; j < 8; ++j) z_sh[j][tid] = acc[j] + bias;
    }
    __syncthreads();

    for (int idx = tid; idx < 8 * OUTD; idx += 256) {
        int j = idx / OUTD;
        int t = idx - j * OUTD;
        float z = z_sh[j][t];
        float* p = pw + (size_t)(b0 + j) * PSTRIDE;
        if (t < 64)            p[K_OFF + t] = tanhf(z);
        else if (t == 65)      p[G_OFF] = sigmoidf_(z);
        else if (t == 73)      p[GAMMA_OFF] = softplusf_(z) + 1.f;
        else if (t >= 74 && t < 138) p[E_OFF + (t - 74)] = sigmoidf_(z);
        else if (t >= 138)     p[A_OFF + (t - 138)] = tanhf(z);
    }
    __syncthreads();

    if (tid < 8) {
        int j = tid;
        float* p = pw + (size_t)(b0 + j) * PSTRIDE;
        float ss = 0.f;
        for (int c = 0; c < 64; ++c) {
            float kv = tanhf(z_sh[j][c]);
            ss += kv * kv;
        }
        float kn = fmaxf(sqrtf(ss), 1e-8f);
        float beta = softplusf_(z_sh[j][64]);
        p[COMBO_OFF] = beta / kn;
        float mx = -1e30f;
        for (int q = 0; q < 7; ++q) mx = fmaxf(mx, z_sh[j][66 + q]);
        float ev[7], se = 0.f;
        for (int q = 0; q < 7; ++q) { ev[q] = expf(z_sh[j][66 + q] - mx); se += ev[q]; }
        float inv = 1.f / se;
        for (int q = 0; q < 7; ++q) p[S_OFF + q] = ev[q] * inv;
    }
}

// ---------------------------------------------------------------------------
// Kernel S: sc[b][r] = exp(combo * (k . m_r) / max(||m_r||, eps)).
// 2048 blocks x 256 threads (8 blocks/CU, 32 waves) — streaming read of
// memory with normal loads (allocate in L3 for update's re-read).
// exp fused here so the serial weight kernel does no transcendental pass.
// Max-free softmax is exact: |combo * cos * k_n| <= beta (small).
// ---------------------------------------------------------------------------
__global__ __launch_bounds__(256) void score_kernel(
    const float* __restrict__ memory, const float* __restrict__ pw,
    float* __restrict__ sc)
{
    const int tid = threadIdx.x;
    const int b = blockIdx.x >> 2;
    const int rbase = (blockIdx.x & 3) * 512;
    const int lane16 = tid & 15;
    const int rgrp = tid >> 4;            // 0..15
    const float* p = pw + (size_t)b * PSTRIDE;
    const float4 k4 = *(const float4*)(p + K_OFF + lane16 * 4);
    const float combo = p[COMBO_OFF];
    const float* memb = memory + (size_t)b * RR * CC;

    #pragma unroll 8
    for (int i = 0; i < 32; ++i) {
        int r = rbase + i * 16 + rgrp;
        float4 m4 = *(const float4*)(memb + (size_t)r * CC + lane16 * 4);
        float num = m4.x * k4.x + m4.y * k4.y + m4.z * k4.z + m4.w * k4.w;
        float ssq = m4.x * m4.x + m4.y * m4.y + m4.z * m4.z + m4.w * m4.w;
        #pragma unroll
        for (int m = 1; m < 16; m <<= 1) {
            num += __shfl_xor(num, m, 64);
            ssq += __shfl_xor(ssq, m, 64);
        }
        if (lane16 == 0) {
            float mn = fmaxf(sqrtf(ssq), 1e-8f);
            sc[(size_t)b * RR + r] = __expf(combo * num / mn);
        }
    }
}

// ---------------------------------------------------------------------------
// Kernel W: per-batch: sum(ev) -> gate with prev_w -> 7-tap circular conv
// -> pow -> normalize -> out_w. 512 blocks x 256 threads; rows in LDS.
// ---------------------------------------------------------------------------
__device__ __forceinline__ float block_reduce_sum256(float v, float* red) {
    #pragma unroll
    for (int m = 1; m < 64; m <<= 1) v += __shfl_xor(v, m, 64);
    int wid = threadIdx.x >> 6;
    if ((threadIdx.x & 63) == 0) red[wid] = v;
    __syncthreads();
    float x = red[0] + red[1] + red[2] + red[3];
    __syncthreads();
    return x;
}

__global__ __launch_bounds__(256) void weight_kernel(
    const float* __restrict__ sc, const float* __restrict__ prev_w,
    const float* __restrict__ pw, float* __restrict__ out_w)
{
    __shared__ float buf[RR];
    __shared__ float wg[RR];
    __shared__ float red[4];
    const int b = blockIdx.x;
    const int tid = threadIdx.x;
    const float* p = pw + (size_t)b * PSTRIDE;
    const float g = p[G_OFF];
    const float gamma = p[GAMMA_OFF];
    const float s0 = p[S_OFF + 0], s1 = p[S_OFF + 1], s2 = p[S_OFF + 2],
                s3 = p[S_OFF + 3], s4 = p[S_OFF + 4], s5 = p[S_OFF + 5],
                s6 = p[S_OFF + 6];

    float ls = 0.f;
    for (int r = tid; r < RR; r += 256) {
        float ev = sc[(size_t)b * RR + r];
        buf[r] = ev;
        ls += ev;
    }
    const float se = block_reduce_sum256(ls, red);
    const float invse = 1.f / se;

    for (int r = tid; r < RR; r += 256) {
        wg[r] = g * (buf[r] * invse) + (1.f - g) * prev_w[(size_t)b * RR + r];
    }
    __syncthreads();

    float lp = 0.f;
    for (int r = tid; r < RR; r += 256) {
        float acc = s0 * wg[(r - 3) & (RR - 1)]
                  + s1 * wg[(r - 2) & (RR - 1)]
                  + s2 * wg[(r - 1) & (RR - 1)]
                  + s3 * wg[r]
                  + s4 * wg[(r + 1) & (RR - 1)]
                  + s5 * wg[(r + 2) & (RR - 1)]
                  + s6 * wg[(r + 3) & (RR - 1)];
        float wp = __powf(acc, gamma);
        buf[r] = wp;
        lp += wp;
    }
    const float ps = block_reduce_sum256(lp, red);
    const float invp = 1.f / (ps + 1e-16f);

    for (int r = tid; r < RR; r += 256) {
        out_w[(size_t)b * RR + r] = buf[r] * invp;
    }
}

// ---------------------------------------------------------------------------
// Kernel U: new_mem = mem*(1 - w*e) + w*a.
// 2048 blocks x 256 threads, per-(batch,quarter) chunks like score but in
// REVERSE block order: score filled L3 front-to-back; reading back-to-front
// hits the MRU end first and pushes write-evictions onto lines read last.
// NT loads (last use — don't re-promote), NT stores (don't allocate).
// ---------------------------------------------------------------------------
__global__ __launch_bounds__(256) void update_kernel(
    const float* __restrict__ memory, const float* __restrict__ w,
    const float* __restrict__ pw, float* __restrict__ out_mem)
{
    const int bid = (int)gridDim.x - 1 - (int)blockIdx.x;
    const int b = bid >> 2;
    const int rbase = (bid & 3) * 512;
    const int tid = threadIdx.x;
    const int lane16 = tid & 15;
    const int rgrp = tid >> 4;            // 0..15
    const float* p = pw + (size_t)b * PSTRIDE;
    const f32x4 e4 = *(const f32x4*)(p + E_OFF + lane16 * 4);
    const f32x4 a4 = *(const f32x4*)(p + A_OFF + lane16 * 4);
    const float* memb = memory + (size_t)b * RR * CC;
    float* omb = out_mem + (size_t)b * RR * CC;
    const float* wb = w + (size_t)b * RR;

    #pragma unroll 8
    for (int i = 0; i < 32; ++i) {
        int r = rbase + i * 16 + rgrp;
        float wv = wb[r];
        const f32x4* mp = (const f32x4*)(memb + (size_t)r * CC) + lane16;
        f32x4 m4 = __builtin_nontemporal_load(mp);
        f32x4 o;
        o.x = m4.x * (1.f - wv * e4.x) + wv * a4.x;
        o.y = m4.y * (1.f - wv * e4.y) + wv * a4.y;
        o.z = m4.z * (1.f - wv * e4.z) + wv * a4.z;
        o.w = m4.w * (1.f - wv * e4.w) + wv * a4.w;
        __builtin_nontemporal_store(o, (f32x4*)(omb + (size_t)r * CC) + lane16);
    }
}

extern "C" void kernel_launch(void* const* d_in, const int* in_sizes, int n_in,
                              void* d_out, int out_size, void* d_ws, size_t ws_size,
                              hipStream_t stream) {
    const float* h      = (const float*)d_in[0];
    const float* prev_w = (const float*)d_in[1];
    const float* memory = (const float*)d_in[2];
    const float* fc_w   = (const float*)d_in[3];
    const float* fc_b   = (const float*)d_in[4];

    float* pw      = (float*)d_ws;              // 512*208*4 = 416 KB
    float* out_w   = (float*)d_out;             // B*R
    float* out_mem = out_w + (size_t)BB * RR;   // B*R*C
    // scratch for exp-scores: head of out_mem region (4 MB), fully
    // overwritten by update_kernel afterwards and never read by it.
    float* sc      = out_mem;

    params_kernel<<<64, 256, 0, stream>>>(h, fc_w, fc_b, pw);
    score_kernel<<<BB * 4, 256, 0, stream>>>(memory, pw, sc);
    weight_kernel<<<BB, 256, 0, stream>>>(sc, prev_w, pw, out_w);
    update_kernel<<<BB * 4, 256, 0, stream>>>(memory, out_w, pw, out_mem);
}

// Round 4
// 193.544 us; speedup vs baseline: 1.2232x; 1.0288x over previous
//
#include <hip/hip_runtime.h>
#include <math.h>

// Problem constants (from reference setup_inputs)
#define BB 512
#define HH 512
#define RR 2048
#define CC 64
#define OUTD 202          // 3*64 + 2*3 + 4
// params workspace layout per batch (floats)
#define PSTRIDE 208
#define K_OFF 0
#define E_OFF 64
#define A_OFF 128
#define S_OFF 192         // 7 softmaxed shift weights
#define COMBO_OFF 199     // beta / k_n
#define G_OFF 200
#define GAMMA_OFF 201

typedef float f32x4 __attribute__((ext_vector_type(4)));

__device__ __forceinline__ float softplusf_(float x) {
    return (x > 20.f) ? x : log1pf(expf(x));
}
__device__ __forceinline__ float sigmoidf_(float x) {
    return 1.f / (1.f + expf(-x));
}

// ---------------------------------------------------------------------------
// Kernel A: z = h @ fc_w^T + fc_b, activations -> packed params in ws.
// ---------------------------------------------------------------------------
__global__ __launch_bounds__(256) void params_kernel(
    const float* __restrict__ h, const float* __restrict__ fc_w,
    const float* __restrict__ fc_b, float* __restrict__ pw)
{
    __shared__ float h_sh[8][HH];
    __shared__ float z_sh[8][204];
    const int tid = threadIdx.x;
    const int b0 = blockIdx.x * 8;

    for (int idx = tid; idx < 8 * HH; idx += 256) {
        int j = idx >> 9, i = idx & 511;
        h_sh[j][i] = h[(size_t)(b0 + j) * HH + i];
    }
    __syncthreads();

    if (tid < OUTD) {
        float acc[8];
        #pragma unroll
        for (int j = 0; j < 8; ++j) acc[j] = 0.f;
        const float4* wr4 = (const float4*)(fc_w + (size_t)tid * HH);
        for (int i4 = 0; i4 < HH / 4; ++i4) {
            float4 wv = wr4[i4];
            int i = i4 * 4;
            #pragma unroll
            for (int j = 0; j < 8; ++j) {
                acc[j] = fmaf(wv.x, h_sh[j][i + 0], acc[j]);
                acc[j] = fmaf(wv.y, h_sh[j][i + 1], acc[j]);
                acc[j] = fmaf(wv.z, h_sh[j][i + 2], acc[j]);
                acc[j] = fmaf(wv.w, h_sh[j][i + 3], acc[j]);
            }
        }
        float bias = fc_b[tid];
        #pragma unroll
        for (int j = 0; j < 8; ++j) z_sh[j][tid] = acc[j] + bias;
    }
    __syncthreads();

    for (int idx = tid; idx < 8 * OUTD; idx += 256) {
        int j = idx / OUTD;
        int t = idx - j * OUTD;
        float z = z_sh[j][t];
        float* p = pw + (size_t)(b0 + j) * PSTRIDE;
        if (t < 64)            p[K_OFF + t] = tanhf(z);
        else if (t == 65)      p[G_OFF] = sigmoidf_(z);
        else if (t == 73)      p[GAMMA_OFF] = softplusf_(z) + 1.f;
        else if (t >= 74 && t < 138) p[E_OFF + (t - 74)] = sigmoidf_(z);
        else if (t >= 138)     p[A_OFF + (t - 138)] = tanhf(z);
    }
    __syncthreads();

    if (tid < 8) {
        int j = tid;
        float* p = pw + (size_t)(b0 + j) * PSTRIDE;
        float ss = 0.f;
        for (int c = 0; c < 64; ++c) {
            float kv = tanhf(z_sh[j][c]);
            ss += kv * kv;
        }
        float kn = fmaxf(sqrtf(ss), 1e-8f);
        float beta = softplusf_(z_sh[j][64]);
        p[COMBO_OFF] = beta / kn;
        float mx = -1e30f;
        for (int q = 0; q < 7; ++q) mx = fmaxf(mx, z_sh[j][66 + q]);
        float ev[7], se = 0.f;
        for (int q = 0; q < 7; ++q) { ev[q] = expf(z_sh[j][66 + q] - mx); se += ev[q]; }
        float inv = 1.f / se;
        for (int q = 0; q < 7; ++q) p[S_OFF + q] = ev[q] * inv;
    }
}

// ---------------------------------------------------------------------------
// Kernel S: sc[b][r] = exp(combo * (k . m_r) / max(||m_r||, eps)).
// 2048 blocks x 256 threads. Normal loads: allocate in L3 so the fused
// kernel's re-read of memory hits. Max-free softmax is exact (|arg|<=beta).
// ---------------------------------------------------------------------------
__global__ __launch_bounds__(256) void score_kernel(
    const float* __restrict__ memory, const float* __restrict__ pw,
    float* __restrict__ sc)
{
    const int tid = threadIdx.x;
    const int b = blockIdx.x >> 2;
    const int rbase = (blockIdx.x & 3) * 512;
    const int lane16 = tid & 15;
    const int rgrp = tid >> 4;            // 0..15
    const float* p = pw + (size_t)b * PSTRIDE;
    const float4 k4 = *(const float4*)(p + K_OFF + lane16 * 4);
    const float combo = p[COMBO_OFF];
    const float* memb = memory + (size_t)b * RR * CC;

    #pragma unroll 8
    for (int i = 0; i < 32; ++i) {
        int r = rbase + i * 16 + rgrp;
        float4 m4 = *(const float4*)(memb + (size_t)r * CC + lane16 * 4);
        float num = m4.x * k4.x + m4.y * k4.y + m4.z * k4.z + m4.w * k4.w;
        float ssq = m4.x * m4.x + m4.y * m4.y + m4.z * m4.z + m4.w * m4.w;
        #pragma unroll
        for (int m = 1; m < 16; m <<= 1) {
            num += __shfl_xor(num, m, 64);
            ssq += __shfl_xor(ssq, m, 64);
        }
        if (lane16 == 0) {
            float mn = fmaxf(sqrtf(ssq), 1e-8f);
            sc[(size_t)b * RR + r] = __expf(combo * num / mn);
        }
    }
}

// ---------------------------------------------------------------------------
// 16-wave block reduce (1024 threads)
// ---------------------------------------------------------------------------
__device__ __forceinline__ float block_reduce_sum16(float v, float* red) {
    #pragma unroll
    for (int m = 1; m < 64; m <<= 1) v += __shfl_xor(v, m, 64);
    int wid = threadIdx.x >> 6;
    if ((threadIdx.x & 63) == 0) red[wid] = v;
    __syncthreads();
    if (threadIdx.x < 16) {
        float x = red[threadIdx.x];
        #pragma unroll
        for (int m = 1; m < 16; m <<= 1) x += __shfl_xor(x, m, 64);
        if (threadIdx.x == 0) red[0] = x;
    }
    __syncthreads();
    float r = red[0];
    __syncthreads();
    return r;
}

// ---------------------------------------------------------------------------
// Kernel WU (fused): per-batch weight pipeline in LDS, then memory update.
// 512 blocks x 1024 threads, one batch per block, REVERSE batch order.
// Blocks naturally desync: one block's VALU weight phase overlaps other
// blocks' streaming phase. w stays in LDS (no HBM round trip).
// ---------------------------------------------------------------------------
__global__ __launch_bounds__(1024) void weight_update_kernel(
    const float* __restrict__ memory, const float* __restrict__ sc,
    const float* __restrict__ prev_w, const float* __restrict__ pw,
    float* __restrict__ out_w, float* __restrict__ out_mem)
{
    __shared__ float buf[RR];
    __shared__ float wg[RR];
    __shared__ float red[16];

    const int b = (int)gridDim.x - 1 - (int)blockIdx.x;
    const int tid = threadIdx.x;
    const float* p = pw + (size_t)b * PSTRIDE;
    const float g = p[G_OFF];
    const float gamma = p[GAMMA_OFF];
    const float s0 = p[S_OFF + 0], s1 = p[S_OFF + 1], s2 = p[S_OFF + 2],
                s3 = p[S_OFF + 3], s4 = p[S_OFF + 4], s5 = p[S_OFF + 5],
                s6 = p[S_OFF + 6];

    // ---- phase A: softmax-sum -> gate -> conv -> pow -> normalize ----
    float ls = 0.f;
    for (int r = tid; r < RR; r += 1024) {
        float ev = sc[(size_t)b * RR + r];
        buf[r] = ev;
        ls += ev;
    }
    const float se = block_reduce_sum16(ls, red);
    const float invse = 1.f / se;

    for (int r = tid; r < RR; r += 1024) {
        wg[r] = g * (buf[r] * invse) + (1.f - g) * prev_w[(size_t)b * RR + r];
    }
    __syncthreads();

    float lp = 0.f;
    for (int r = tid; r < RR; r += 1024) {
        float acc = s0 * wg[(r - 3) & (RR - 1)]
                  + s1 * wg[(r - 2) & (RR - 1)]
                  + s2 * wg[(r - 1) & (RR - 1)]
                  + s3 * wg[r]
                  + s4 * wg[(r + 1) & (RR - 1)]
                  + s5 * wg[(r + 2) & (RR - 1)]
                  + s6 * wg[(r + 3) & (RR - 1)];
        float wp = __powf(acc, gamma);
        buf[r] = wp;
        lp += wp;
    }
    // reduce has an internal barrier, so all conv reads of wg are done
    const float ps = block_reduce_sum16(lp, red);
    const float invp = 1.f / (ps + 1e-16f);

    for (int r = tid; r < RR; r += 1024) {
        float wv = buf[r] * invp;
        wg[r] = wv;                                      // final w for phase B
        __builtin_nontemporal_store(wv, out_w + (size_t)b * RR + r);
    }
    __syncthreads();

    // ---- phase B: new_mem = mem*(1 - w*e) + w*a ----
    const int lane16 = tid & 15;
    const int rgrp = tid >> 4;                           // 0..63
    const f32x4 e4 = *(const f32x4*)(p + E_OFF + lane16 * 4);
    const f32x4 a4 = *(const f32x4*)(p + A_OFF + lane16 * 4);
    const float* memb = memory + (size_t)b * RR * CC;
    float* omb = out_mem + (size_t)b * RR * CC;

    #pragma unroll 8
    for (int i = 0; i < 32; ++i) {
        int r = i * 64 + rgrp;
        float wv = wg[r];
        f32x4 m4 = __builtin_nontemporal_load(
            (const f32x4*)(memb + (size_t)r * CC) + lane16);
        f32x4 o;
        o.x = m4.x * (1.f - wv * e4.x) + wv * a4.x;
        o.y = m4.y * (1.f - wv * e4.y) + wv * a4.y;
        o.z = m4.z * (1.f - wv * e4.z) + wv * a4.z;
        o.w = m4.w * (1.f - wv * e4.w) + wv * a4.w;
        __builtin_nontemporal_store(o, (f32x4*)(omb + (size_t)r * CC) + lane16);
    }
}

// ---------------------------------------------------------------------------
// Fallback path (ws too small for sc): round-3 separate kernels, sc aliased
// onto out_mem (safe only because weight/update are separate dispatches).
// ---------------------------------------------------------------------------
__device__ __forceinline__ float block_reduce_sum4(float v, float* red) {
    #pragma unroll
    for (int m = 1; m < 64; m <<= 1) v += __shfl_xor(v, m, 64);
    int wid = threadIdx.x >> 6;
    if ((threadIdx.x & 63) == 0) red[wid] = v;
    __syncthreads();
    float x = red[0] + red[1] + red[2] + red[3];
    __syncthreads();
    return x;
}

__global__ __launch_bounds__(256) void weight_kernel(
    const float* __restrict__ sc, const float* __restrict__ prev_w,
    const float* __restrict__ pw, float* __restrict__ out_w)
{
    __shared__ float buf[RR];
    __shared__ float wg[RR];
    __shared__ float red[4];
    const int b = blockIdx.x;
    const int tid = threadIdx.x;
    const float* p = pw + (size_t)b * PSTRIDE;
    const float g = p[G_OFF];
    const float gamma = p[GAMMA_OFF];
    const float s0 = p[S_OFF + 0], s1 = p[S_OFF + 1], s2 = p[S_OFF + 2],
                s3 = p[S_OFF + 3], s4 = p[S_OFF + 4], s5 = p[S_OFF + 5],
                s6 = p[S_OFF + 6];

    float ls = 0.f;
    for (int r = tid; r < RR; r += 256) {
        float ev = sc[(size_t)b * RR + r];
        buf[r] = ev;
        ls += ev;
    }
    const float se = block_reduce_sum4(ls, red);
    const float invse = 1.f / se;

    for (int r = tid; r < RR; r += 256) {
        wg[r] = g * (buf[r] * invse) + (1.f - g) * prev_w[(size_t)b * RR + r];
    }
    __syncthreads();

    float lp = 0.f;
    for (int r = tid; r < RR; r += 256) {
        float acc = s0 * wg[(r - 3) & (RR - 1)]
                  + s1 * wg[(r - 2) & (RR - 1)]
                  + s2 * wg[(r - 1) & (RR - 1)]
                  + s3 * wg[r]
                  + s4 * wg[(r + 1) & (RR - 1)]
                  + s5 * wg[(r + 2) & (RR - 1)]
                  + s6 * wg[(r + 3) & (RR - 1)];
        float wp = __powf(acc, gamma);
        buf[r] = wp;
        lp += wp;
    }
    const float ps = block_reduce_sum4(lp, red);
    const float invp = 1.f / (ps + 1e-16f);

    for (int r = tid; r < RR; r += 256) {
        out_w[(size_t)b * RR + r] = buf[r] * invp;
    }
}

__global__ __launch_bounds__(256) void update_kernel(
    const float* __restrict__ memory, const float* __restrict__ w,
    const float* __restrict__ pw, float* __restrict__ out_mem)
{
    const int bid = (int)gridDim.x - 1 - (int)blockIdx.x;
    const int b = bid >> 2;
    const int rbase = (bid & 3) * 512;
    const int tid = threadIdx.x;
    const int lane16 = tid & 15;
    const int rgrp = tid >> 4;
    const float* p = pw + (size_t)b * PSTRIDE;
    const f32x4 e4 = *(const f32x4*)(p + E_OFF + lane16 * 4);
    const f32x4 a4 = *(const f32x4*)(p + A_OFF + lane16 * 4);
    const float* memb = memory + (size_t)b * RR * CC;
    float* omb = out_mem + (size_t)b * RR * CC;
    const float* wb = w + (size_t)b * RR;

    #pragma unroll 8
    for (int i = 0; i < 32; ++i) {
        int r = rbase + i * 16 + rgrp;
        float wv = wb[r];
        f32x4 m4 = __builtin_nontemporal_load(
            (const f32x4*)(memb + (size_t)r * CC) + lane16);
        f32x4 o;
        o.x = m4.x * (1.f - wv * e4.x) + wv * a4.x;
        o.y = m4.y * (1.f - wv * e4.y) + wv * a4.y;
        o.z = m4.z * (1.f - wv * e4.z) + wv * a4.z;
        o.w = m4.w * (1.f - wv * e4.w) + wv * a4.w;
        __builtin_nontemporal_store(o, (f32x4*)(omb + (size_t)r * CC) + lane16);
    }
}

extern "C" void kernel_launch(void* const* d_in, const int* in_sizes, int n_in,
                              void* d_out, int out_size, void* d_ws, size_t ws_size,
                              hipStream_t stream) {
    const float* h      = (const float*)d_in[0];
    const float* prev_w = (const float*)d_in[1];
    const float* memory = (const float*)d_in[2];
    const float* fc_w   = (const float*)d_in[3];
    const float* fc_b   = (const float*)d_in[4];

    float* pw      = (float*)d_ws;              // 512*208*4 = 416 KB
    float* out_w   = (float*)d_out;             // B*R
    float* out_mem = out_w + (size_t)BB * RR;   // B*R*C

    const size_t pw_bytes = (size_t)BB * PSTRIDE * sizeof(float);
    const size_t sc_bytes = (size_t)BB * RR * sizeof(float);

    params_kernel<<<64, 256, 0, stream>>>(h, fc_w, fc_b, pw);

    if (ws_size >= pw_bytes + sc_bytes) {
        // sc lives in d_ws -> safe to fuse weight+update in one kernel
        float* sc = pw + (size_t)BB * PSTRIDE;
        score_kernel<<<BB * 4, 256, 0, stream>>>(memory, pw, sc);
        weight_update_kernel<<<BB, 1024, 0, stream>>>(
            memory, sc, prev_w, pw, out_w, out_mem);
    } else {
        // fallback: sc aliased onto out_mem; weight/update as separate
        // dispatches (kernel boundary orders the reads before overwrites)
        float* sc = out_mem;
        score_kernel<<<BB * 4, 256, 0, stream>>>(memory, pw, sc);
        weight_kernel<<<BB, 256, 0, stream>>>(sc, prev_w, pw, out_w);
        update_kernel<<<BB * 4, 256, 0, stream>>>(memory, out_w, pw, out_mem);
    }
}